// Round 10
// baseline (563.679 us; speedup 1.0000x reference)
//
#include <hip/hip_runtime.h>
#include <hip/hip_bf16.h>
#include <math.h>

// Problem shape (fixed): B=32, S=4096, D=1024, L=1
#define D_DIM 1024
#define S_DIM 4096
#define B_DIM 32
#define M_TOTAL (B_DIM * S_DIM)   // 131072 rows

using short8 = __attribute__((ext_vector_type(8))) short;
using f32x4  = __attribute__((ext_vector_type(4))) float;

// fp32 -> bf16, round-to-nearest-even (one-time weight conversion kernels)
static __device__ __forceinline__ unsigned short f2bf(float x) {
    unsigned int u = __float_as_uint(x);
    u += 0x7fffu + ((u >> 16) & 1u);
    return (unsigned short)(u >> 16);
}

// packed bf16 pair via HW v_cvt_pk_bf16_f32 (RNE) — same rounding as f2bf
static __device__ __forceinline__ unsigned int pk2(float lo, float hi) {
    __hip_bfloat162 h = __float22bfloat162_rn(float2{lo, hi});
    unsigned int u; __builtin_memcpy(&u, &h, 4); return u;
}

// tanh via exp2-backed __expf; ~1e-6 abs err (we need ~1e-3)
static __device__ __forceinline__ float fast_tanh(float x) {
    float e2 = __expf(2.0f * x);
    return 1.0f - 2.0f * __builtin_amdgcn_rcpf(e2 + 1.0f);
}

// ---------------------------------------------------------------------------
// Detect attn_mask dtype: int32 (0/1 -> high bytes of every word are 0)
// vs. bool/uint8 (random 0/1 bytes -> some high byte nonzero).
__global__ __launch_bounds__(256) void mask_detect_kernel(
        const unsigned int* __restrict__ m, int* __restrict__ flag) {
    __shared__ unsigned int red[4];
    int t = threadIdx.x;
    unsigned int acc = 0;
    for (int i = t; i < 32768; i += 256) acc |= (m[i] & 0xFFFFFF00u);
    #pragma unroll
    for (int k = 1; k <= 32; k <<= 1) acc |= __shfl_xor(acc, k, 64);
    if ((t & 63) == 0) red[t >> 6] = acc;
    __syncthreads();
    if (t == 0) flag[0] = ((red[0] | red[1] | red[2] | red[3]) != 0) ? 1 : 0;
}

// ---------------------------------------------------------------------------
// Convert Wa_w [1024][1024] fp32 -> bf16 in FRAGMENT-TILED layout:
//   Wt[((et*32 + kc)*64 + lane)*8 + j] = bf16( W[et*16 + (lane&15)]
//                                              [kc*32 + (lane>>4)*8 + j] )
// One wave's B-fragment load = one coalesced 1 KiB read.  (R7 verbatim)
__global__ __launch_bounds__(256) void wconv_kernel(
        const float* __restrict__ W, unsigned short* __restrict__ Wt) {
    int tid  = blockIdx.x * 256 + threadIdx.x;   // 0..131071, one short8 each
    int lane = tid & 63;
    int kc   = (tid >> 6) & 31;
    int et   = tid >> 11;
    int e = et * 16 + (lane & 15);
    int k = kc * 32 + (lane >> 4) * 8;
    const float* src = W + (size_t)e * D_DIM + k;
    float4 v0 = *(const float4*)(src);
    float4 v1 = *(const float4*)(src + 4);
    short8 pk;
    pk[0] = (short)f2bf(v0.x); pk[1] = (short)f2bf(v0.y);
    pk[2] = (short)f2bf(v0.z); pk[3] = (short)f2bf(v0.w);
    pk[4] = (short)f2bf(v1.x); pk[5] = (short)f2bf(v1.y);
    pk[6] = (short)f2bf(v1.z); pk[7] = (short)f2bf(v1.w);
    *(short8*)(Wt + (size_t)tid * 8) = pk;
}

// ---------------------------------------------------------------------------
// off[b][e] = sum_d h[0][b][d]*Ua_w[e][d] + Ua_b[e] + Wa_b[e]  (R4 verbatim)
__global__ __launch_bounds__(256) void off_kernel(
        const float* __restrict__ h, const float* __restrict__ Uw,
        const float* __restrict__ Ub, const float* __restrict__ Wab,
        float* __restrict__ off) {
    int wg   = blockIdx.x * 4 + (threadIdx.x >> 6);
    int lane = threadIdx.x & 63;
    int b = wg >> 10, e = wg & 1023;
    const float4* h4 = (const float4*)(h + (size_t)b * D_DIM);
    const float4* u4 = (const float4*)(Uw + (size_t)e * D_DIM);
    float s = 0.f;
    #pragma unroll
    for (int c = 0; c < 4; ++c) {
        float4 a = h4[c * 64 + lane];
        float4 w = u4[c * 64 + lane];
        s += a.x * w.x + a.y * w.y + a.z * w.z + a.w * w.w;
    }
    #pragma unroll
    for (int m = 32; m; m >>= 1) s += __shfl_xor(s, m, 64);
    if (lane == 0) off[b * D_DIM + e] = s + Ub[e] + Wab[e];
}

// ---------------------------------------------------------------------------
// Zero the score accumulation buffer (col-blocks atomicAdd into it).
__global__ __launch_bounds__(256) void zero_kernel(float* __restrict__ p) {
    ((float4*)p)[blockIdx.x * 256 + threadIdx.x] = (float4){0.f, 0.f, 0.f, 0.f};
}

// ---------------------------------------------------------------------------
// Fused partial scores, BIG-TILE (m201 geometry):
//   block = 256 rows x 256 cols; 8 waves of 128x64 (acc[8][4] = 128 VGPR);
//   BK=64 -> 16 K-tiles, ONE __syncthreads per tile.
// Per-tile compute ~2500 cy/CU >> every memory shadow, so all loads are a
// full tile (or half-tile) old at consumption and the barrier drain is free:
//   [issue A-chunk0 (t+1)] [issue B(kg1)] [kg0: 32 MFMA] [cvt+write chunk0]
//   [issue A-chunk1 (t+1)] [issue B(kg0, t+1)] [kg1: 32 MFMA] [cvt+write
//   chunk1] [barrier]
// B register-double-buffered from L2-resident fragment-tiled Wt.
// XCD swizzle: a panel's 4 col-blocks sit consecutively on one XCD ->
// 3 of 4 A-panel reads are L2 hits (HBM stays 512 MB).
// 1 block/CU (LDS 66 KB, ~220 VGPR), launch_bounds(512,2).
__global__ __launch_bounds__(512, 2) void score_kernel(
        const float* __restrict__ A,            // [M][1024] fp32
        const unsigned short* __restrict__ Wt,  // tiled bf16 (see wconv)
        const float* __restrict__ off,          // [32][1024]
        const float* __restrict__ Va,           // [1024]
        float* __restrict__ scores)             // [M] accumulated
{
    __shared__ short As[2][256 * 64];   // 2 x 32 KiB bf16, XOR-swizzled rows
    __shared__ float score_lds[256];

    // XCD swizzle: bid%8 = XCD; per XCD, consecutive idx = the 4 col-blocks
    // of one 256-row panel.
    const int bid   = blockIdx.x;                 // 0..2047
    const int idx   = bid >> 3;                   // 0..255
    const int panel = (bid & 7) * 64 + (idx >> 2);// 0..511
    const int colq  = idx & 3;                    // column block (256 cols)
    const int row0  = panel * 256;
    const int b     = panel >> 4;                 // 16 panels per batch

    const int t = threadIdx.x;
    if (t < 256) score_lds[t] = 0.f;

    const int wave = t >> 6, lane = t & 63;
    const int l15 = lane & 15, lhi = lane >> 4;
    const int wr = wave >> 2;          // row half (128 rows)
    const int wc = wave & 3;           // col quarter (64 cols)
    const int et0 = colq * 16 + wc * 4;

    // A staging: thread covers row r, 32 consecutive k-floats (two chunks)
    const int sr = t >> 1;              // row 0..255
    const int kh = (t & 1) * 32;        // float col base 0 or 32
    const float* asrc = A + (size_t)(row0 + sr) * D_DIM + kh;
    const int swz = (sr & 7) << 4;      // byte-XOR within the 128-B row

    f32x4 acc[8][4];
    #pragma unroll
    for (int rf = 0; rf < 8; ++rf)
        #pragma unroll
        for (int cf = 0; cf < 4; ++cf) acc[rf][cf] = (f32x4){0.f, 0.f, 0.f, 0.f};

    short8 bA[4], bB[4];

    #define LOADB(SET, KC) do {                                              \
        _Pragma("unroll")                                                    \
        for (int cf = 0; cf < 4; ++cf)                                       \
            SET[cf] = *(const short8*)(Wt                                    \
                + ((size_t)((et0 + cf) * 32 + (KC))) * 512 + lane * 8);      \
    } while (0)

    #define KGSTEP(KG, BFR) do {                                             \
        short8 af[8];                                                        \
        _Pragma("unroll")                                                    \
        for (int rf = 0; rf < 8; ++rf) {                                     \
            int row = wr * 128 + rf * 16 + l15;                              \
            af[rf] = *(const short8*)((const char*)As[cur] + row * 128       \
                       + (((KG) * 64 + lhi * 16) ^ ((row & 7) << 4)));       \
        }                                                                    \
        __builtin_amdgcn_s_setprio(1);                                       \
        _Pragma("unroll")                                                    \
        for (int rf = 0; rf < 8; ++rf)                                       \
            _Pragma("unroll")                                                \
            for (int cf = 0; cf < 4; ++cf)                                   \
                acc[rf][cf] = __builtin_amdgcn_mfma_f32_16x16x32_bf16(       \
                    af[rf], BFR[cf], acc[rf][cf], 0, 0, 0);                  \
        __builtin_amdgcn_s_setprio(0);                                       \
    } while (0)

    #define CVT2(P0, P1, BYTECOL) do {                                       \
        uint4 o_;                                                            \
        o_.x = pk2(P0.x, P0.y); o_.y = pk2(P0.z, P0.w);                      \
        o_.z = pk2(P1.x, P1.y); o_.w = pk2(P1.z, P1.w);                      \
        *(uint4*)((char*)As[cur ^ 1] + sr * 128 + ((BYTECOL) ^ swz)) = o_;   \
    } while (0)

    // ---- prologue: stage tile 0 directly + first B set ----
    {
        float4 v0 = *(const float4*)(asrc + 0);
        float4 v1 = *(const float4*)(asrc + 4);
        float4 v2 = *(const float4*)(asrc + 8);
        float4 v3 = *(const float4*)(asrc + 12);
        float4 v4 = *(const float4*)(asrc + 16);
        float4 v5 = *(const float4*)(asrc + 20);
        float4 v6 = *(const float4*)(asrc + 24);
        float4 v7 = *(const float4*)(asrc + 28);
        uint4 o;
        char* dst = (char*)As[0] + sr * 128;
        o.x = pk2(v0.x, v0.y); o.y = pk2(v0.z, v0.w);
        o.z = pk2(v1.x, v1.y); o.w = pk2(v1.z, v1.w);
        *(uint4*)(dst + ((kh * 2 +  0) ^ swz)) = o;
        o.x = pk2(v2.x, v2.y); o.y = pk2(v2.z, v2.w);
        o.z = pk2(v3.x, v3.y); o.w = pk2(v3.z, v3.w);
        *(uint4*)(dst + ((kh * 2 + 16) ^ swz)) = o;
        o.x = pk2(v4.x, v4.y); o.y = pk2(v4.z, v4.w);
        o.z = pk2(v5.x, v5.y); o.w = pk2(v5.z, v5.w);
        *(uint4*)(dst + ((kh * 2 + 32) ^ swz)) = o;
        o.x = pk2(v6.x, v6.y); o.y = pk2(v6.z, v6.w);
        o.z = pk2(v7.x, v7.y); o.w = pk2(v7.z, v7.w);
        *(uint4*)(dst + ((kh * 2 + 48) ^ swz)) = o;
    }
    LOADB(bA, 0);
    __syncthreads();

    for (int tile = 0; tile < 16; ++tile) {
        const int cur = tile & 1;
        const float* nx = asrc + (tile + 1) * 64;

        // issue A chunk0 (t+1) — consumed after kg0 (~1300 cy)
        float4 q0, q1, q2, q3;
        if (tile < 15) {
            q0 = *(const float4*)(nx + 0);
            q1 = *(const float4*)(nx + 4);
            q2 = *(const float4*)(nx + 8);
            q3 = *(const float4*)(nx + 12);
        }
        // issue B(kg1) — consumed after kg0
        LOADB(bB, tile * 2 + 1);

        KGSTEP(0, bA);

        if (tile < 15) {
            CVT2(q0, q1, kh * 2 + 0);
            CVT2(q2, q3, kh * 2 + 16);
        }
        // issue A chunk1 (t+1) — consumed after kg1
        float4 q4, q5, q6, q7;
        if (tile < 15) {
            q4 = *(const float4*)(nx + 16);
            q5 = *(const float4*)(nx + 20);
            q6 = *(const float4*)(nx + 24);
            q7 = *(const float4*)(nx + 28);
            // issue B(kg0, t+1) — consumed after next tile starts
            LOADB(bA, (tile + 1) * 2);
        }

        KGSTEP(1, bB);

        if (tile < 15) {
            CVT2(q4, q5, kh * 2 + 32);
            CVT2(q6, q7, kh * 2 + 48);
        }
        __syncthreads();
    }

    // ---- epilogue: tanh + Va-weighted reduction over this wave's 64 cols ----
    // C/D layout (m89-verified): col = lane&15, row = (lane>>4)*4 + reg
    float sp[8][4];
    #pragma unroll
    for (int rf = 0; rf < 8; ++rf)
        #pragma unroll
        for (int j = 0; j < 4; ++j) sp[rf][j] = 0.f;

    #pragma unroll
    for (int cf = 0; cf < 4; ++cf) {
        int e = colq * 256 + wc * 64 + cf * 16 + l15;
        float offv = off[b * D_DIM + e];
        float vav  = Va[e];
        #pragma unroll
        for (int rf = 0; rf < 8; ++rf)
            #pragma unroll
            for (int j = 0; j < 4; ++j) {
                float x = acc[rf][cf][j] + offv;
                sp[rf][j] += fast_tanh(x) * vav;
            }
    }

    #pragma unroll
    for (int rf = 0; rf < 8; ++rf)
        #pragma unroll
        for (int j = 0; j < 4; ++j) {
            float v = sp[rf][j];
            v += __shfl_xor(v, 1, 64);
            v += __shfl_xor(v, 2, 64);
            v += __shfl_xor(v, 4, 64);
            v += __shfl_xor(v, 8, 64);
            if (l15 == 0)
                atomicAdd(&score_lds[wr * 128 + rf * 16 + lhi * 4 + j], v);
        }
    __syncthreads();

    if (t < 256) atomicAdd(&scores[row0 + t], score_lds[t]);
}

// ---------------------------------------------------------------------------
// Masked softmax over S=4096 per batch row. One block per b.
__global__ __launch_bounds__(256) void softmax_kernel(
        const float* __restrict__ scores, const void* __restrict__ mask,
        const int* __restrict__ flag, float* __restrict__ out) {
    __shared__ float red[4];
    const int b = blockIdx.x, t = threadIdx.x;
    const float* s = scores + (size_t)b * S_DIM;
    const int mode8 = flag[0];

    float v[16];
    float mx = -INFINITY;
    if (mode8) {
        const unsigned char* m = (const unsigned char*)mask + (size_t)b * S_DIM;
        #pragma unroll
        for (int i = 0; i < 16; ++i) {
            int idx = i * 256 + t;
            v[i] = m[idx] ? s[idx] : -INFINITY;
            mx = fmaxf(mx, v[i]);
        }
    } else {
        const int* m = (const int*)mask + (size_t)b * S_DIM;
        #pragma unroll
        for (int i = 0; i < 16; ++i) {
            int idx = i * 256 + t;
            v[i] = m[idx] ? s[idx] : -INFINITY;
            mx = fmaxf(mx, v[i]);
        }
    }
    #pragma unroll
    for (int k = 1; k <= 32; k <<= 1) mx = fmaxf(mx, __shfl_xor(mx, k, 64));
    if ((t & 63) == 0) red[t >> 6] = mx;
    __syncthreads();
    mx = fmaxf(fmaxf(red[0], red[1]), fmaxf(red[2], red[3]));
    __syncthreads();

    float sum = 0.f;
    #pragma unroll
    for (int i = 0; i < 16; ++i) {
        v[i] = __expf(v[i] - mx);     // exp(-inf)=0 for masked slots
        sum += v[i];
    }
    #pragma unroll
    for (int k = 1; k <= 32; k <<= 1) sum += __shfl_xor(sum, k, 64);
    if ((t & 63) == 0) red[t >> 6] = sum;
    __syncthreads();
    sum = red[0] + red[1] + red[2] + red[3];
    float inv = 1.f / sum;
    #pragma unroll
    for (int i = 0; i < 16; ++i) out[(size_t)b * S_DIM + i * 256 + t] = v[i] * inv;
}

// ---------------------------------------------------------------------------
extern "C" void kernel_launch(void* const* d_in, const int* in_sizes, int n_in,
                              void* d_out, int out_size, void* d_ws, size_t ws_size,
                              hipStream_t stream) {
    const float* enc  = (const float*)d_in[0];   // [32][4096][1024]
    const float* dech = (const float*)d_in[1];   // [1][32][1024]
    const void*  mask = d_in[2];                 // [32][4096] bool-or-int32
    const float* Wa_w = (const float*)d_in[3];   // [1024][1024]
    const float* Wa_b = (const float*)d_in[4];   // [1024]
    const float* Ua_w = (const float*)d_in[5];   // [1024][1024]
    const float* Ua_b = (const float*)d_in[6];   // [1024]
    const float* Va_w = (const float*)d_in[7];   // [1][1024]
    // d_in[8] = Va_b: constant shift -> cancels in softmax.
    float* out = (float*)d_out;

    char* ws = (char*)d_ws;
    unsigned short* Wt = (unsigned short*)ws;                       // 2 MiB tiled
    float* off    = (float*)(ws + (1u << 21));                      // 128 KiB
    float* scores = (float*)(ws + (1u << 21) + (1u << 17));         // 512 KiB
    int*   flag   = (int*)(ws + (1u << 21) + (1u << 17) + (1u << 19));

    hipLaunchKernelGGL(mask_detect_kernel, dim3(1), dim3(256), 0, stream,
                       (const unsigned int*)mask, flag);
    hipLaunchKernelGGL(wconv_kernel, dim3(512), dim3(256), 0, stream, Wa_w, Wt);
    hipLaunchKernelGGL(off_kernel, dim3(8192), dim3(256), 0, stream,
                       dech, Ua_w, Ua_b, Wa_b, off);
    hipLaunchKernelGGL(zero_kernel, dim3(128), dim3(256), 0, stream, scores);
    hipLaunchKernelGGL(score_kernel, dim3(2048), dim3(512), 0, stream,
                       enc, Wt, off, Va_w, scores);
    hipLaunchKernelGGL(softmax_kernel, dim3(B_DIM), dim3(256), 0, stream,
                       scores, mask, flag, out);
}

// Round 11
// 523.550 us; speedup vs baseline: 1.0766x; 1.0766x over previous
//
#include <hip/hip_runtime.h>
#include <hip/hip_bf16.h>
#include <math.h>

// Problem shape (fixed): B=32, S=4096, D=1024, L=1
#define D_DIM 1024
#define S_DIM 4096
#define B_DIM 32
#define M_TOTAL (B_DIM * S_DIM)   // 131072 rows

#define KQ   128                  // K per pipeline phase
#define NPH  8                    // phases (8*128 = 1024)

using short8 = __attribute__((ext_vector_type(8))) short;
using f32x4  = __attribute__((ext_vector_type(4))) float;

// fp32 -> bf16, round-to-nearest-even (one-time weight conversion kernels)
static __device__ __forceinline__ unsigned short f2bf(float x) {
    unsigned int u = __float_as_uint(x);
    u += 0x7fffu + ((u >> 16) & 1u);
    return (unsigned short)(u >> 16);
}

// packed bf16 pair via HW v_cvt_pk_bf16_f32 (RNE) — same rounding as f2bf
static __device__ __forceinline__ unsigned int pk2(float lo, float hi) {
    __hip_bfloat162 h = __float22bfloat162_rn(float2{lo, hi});
    unsigned int u; __builtin_memcpy(&u, &h, 4); return u;
}

// tanh via exp2-backed __expf; ~1e-6 abs err (we need ~1e-3)
static __device__ __forceinline__ float fast_tanh(float x) {
    float e2 = __expf(2.0f * x);
    return 1.0f - 2.0f * __builtin_amdgcn_rcpf(e2 + 1.0f);
}

// ---------------------------------------------------------------------------
// Detect attn_mask dtype: int32 (0/1 -> high bytes of every word are 0)
// vs. bool/uint8 (random 0/1 bytes -> some high byte nonzero).
__global__ __launch_bounds__(256) void mask_detect_kernel(
        const unsigned int* __restrict__ m, int* __restrict__ flag) {
    __shared__ unsigned int red[4];
    int t = threadIdx.x;
    unsigned int acc = 0;
    for (int i = t; i < 32768; i += 256) acc |= (m[i] & 0xFFFFFF00u);
    #pragma unroll
    for (int k = 1; k <= 32; k <<= 1) acc |= __shfl_xor(acc, k, 64);
    if ((t & 63) == 0) red[t >> 6] = acc;
    __syncthreads();
    if (t == 0) flag[0] = ((red[0] | red[1] | red[2] | red[3]) != 0) ? 1 : 0;
}

// ---------------------------------------------------------------------------
// Convert Wa_w [1024][1024] fp32 -> bf16 in FRAGMENT-TILED layout:
//   Wt[((et*32 + kc)*64 + lane)*8 + j] = bf16( W[et*16 + (lane&15)]
//                                              [kc*32 + (lane>>4)*8 + j] )
// One wave's B-fragment load = one coalesced 1 KiB read.  (R7 verbatim)
__global__ __launch_bounds__(256) void wconv_kernel(
        const float* __restrict__ W, unsigned short* __restrict__ Wt) {
    int tid  = blockIdx.x * 256 + threadIdx.x;   // 0..131071, one short8 each
    int lane = tid & 63;
    int kc   = (tid >> 6) & 31;
    int et   = tid >> 11;
    int e = et * 16 + (lane & 15);
    int k = kc * 32 + (lane >> 4) * 8;
    const float* src = W + (size_t)e * D_DIM + k;
    float4 v0 = *(const float4*)(src);
    float4 v1 = *(const float4*)(src + 4);
    short8 pk;
    pk[0] = (short)f2bf(v0.x); pk[1] = (short)f2bf(v0.y);
    pk[2] = (short)f2bf(v0.z); pk[3] = (short)f2bf(v0.w);
    pk[4] = (short)f2bf(v1.x); pk[5] = (short)f2bf(v1.y);
    pk[6] = (short)f2bf(v1.z); pk[7] = (short)f2bf(v1.w);
    *(short8*)(Wt + (size_t)tid * 8) = pk;
}

// ---------------------------------------------------------------------------
// off[b][e] = sum_d h[0][b][d]*Ua_w[e][d] + Ua_b[e] + Wa_b[e]
// One block per e: U row read ONCE (4 MiB total); h stays L2-resident. (R5)
__global__ __launch_bounds__(256) void off_kernel(
        const float* __restrict__ h, const float* __restrict__ Uw,
        const float* __restrict__ Ub, const float* __restrict__ Wab,
        float* __restrict__ off) {
    const int e = blockIdx.x;
    const int t = threadIdx.x;
    __shared__ float red[4];
    float4 u = ((const float4*)(Uw + (size_t)e * D_DIM))[t];
    float base = Ub[e] + Wab[e];
    for (int b = 0; b < B_DIM; ++b) {
        float4 a = ((const float4*)(h + (size_t)b * D_DIM))[t];
        float s = a.x * u.x + a.y * u.y + a.z * u.z + a.w * u.w;
        #pragma unroll
        for (int m = 32; m; m >>= 1) s += __shfl_xor(s, m, 64);
        if ((t & 63) == 0) red[t >> 6] = s;
        __syncthreads();
        if (t == 0) off[b * D_DIM + e] = red[0] + red[1] + red[2] + red[3] + base;
        __syncthreads();
    }
}

// ---------------------------------------------------------------------------
// Fused partial scores: for column-half hh,
//   scoresH[row] = sum_{e in half} Va[e] * tanh( (A@W^T)[row][e] + off[b][e] )
//
// 8 waves (512 thr); block = 64 rows x 512 cols; wave tile 32x128 (rf=2,
// cf=8, acc=64 regs). cf=8 halves A-LDS traffic per MFMA: per CU-phase
// A-ds_read = 64 KB (512 cy) < MFMA (621 cy) -> LDS leaves the critical path.
// LDS layout: 128-BYTE pseudo-rows (p = row*2 + k/64) with 16B-granule XOR
// swizzle — the exact layout that measured ZERO bank conflicts in R10.
// A staging is 2-phase-deep: loads for panel q+2 issued at phase q (named
// reg sets S0/S1), converted at q+1, consumed at q+2 — a full phase (~HBM
// latency) of hiding before the barrier drain. B frags ping-pong (BA/BB),
// prefetched one kk-step ahead from L2-resident fragment-tiled Wt.
__global__ __launch_bounds__(512, 2) void score_kernel(
        const float* __restrict__ A,            // [M][1024] fp32
        const unsigned short* __restrict__ Wt,  // tiled bf16 (see wconv)
        const float* __restrict__ off,          // [32][1024]
        const float* __restrict__ Va,           // [1024]
        float* __restrict__ scores)             // [2][M] partial (by half)
{
    __shared__ short As[2][64 * KQ];    // 2 x 16 KiB, 128-B pseudo-row swz
    __shared__ float score_lds[64];

    // XCD-pair swizzle (R4/R7 verbatim): consecutive idx on one XCD are the
    // two column-halves of one row-panel (A L2 reuse).
    const int bid  = blockIdx.x;
    const int pr   = (bid & 7) * 256 + ((bid >> 3) >> 1);   // row-tile 0..2047
    const int hh   = (bid >> 3) & 1;                        // column half
    const int row0 = pr * 64;
    const int b    = row0 >> 12;        // 4096 rows per batch

    const int t = threadIdx.x;
    if (t < 64) score_lds[t] = 0.f;

    const int wave = t >> 6, lane = t & 63;
    const int l15 = lane & 15, lhi = lane >> 4;
    const int wr   = wave >> 2;         // row group (32 rows)
    const int wcol = wave & 3;          // col group (128 cols)
    const int e0 = hh * 512 + wcol * 128;
    const int etb = hh * 32 + wcol * 8; // 16-col tile base

    // staging geometry: thread covers row sr, 16 consecutive k (4 float4)
    const int sr = t >> 3;              // row 0..63
    const int kb = (t & 7) * 16;        // k-base 0..112
    const float* asrc = A + (size_t)(row0 + sr) * D_DIM + kb;
    const int sp_ = sr * 2 + (kb >> 6);             // pseudo-row
    const int sg0 = ((kb & 63) >> 3);               // even granule 0..6
    const int sx  = (sp_ & 7) << 4;                 // byte XOR
    const int sb0 = sp_ * 128 + ((sg0 * 16) ^ sx);
    const int sb1 = sp_ * 128 + (((sg0 + 1) * 16) ^ sx);

    f32x4 acc[2][8];
    #pragma unroll
    for (int rf = 0; rf < 2; ++rf)
        #pragma unroll
        for (int cf = 0; cf < 8; ++cf) acc[rf][cf] = (f32x4){0.f, 0.f, 0.f, 0.f};

    short8 BA[8], BB[8];
    float4 s0a, s0b, s0c, s0d, s1a, s1b, s1c, s1d;  // named stage sets

    #define ISSUE0(Q) do { const float* nx_ = asrc + (Q) * KQ;               \
        s0a = *(const float4*)(nx_ + 0);  s0b = *(const float4*)(nx_ + 4);   \
        s0c = *(const float4*)(nx_ + 8);  s0d = *(const float4*)(nx_ + 12); } while (0)
    #define ISSUE1(Q) do { const float* nx_ = asrc + (Q) * KQ;               \
        s1a = *(const float4*)(nx_ + 0);  s1b = *(const float4*)(nx_ + 4);   \
        s1c = *(const float4*)(nx_ + 8);  s1d = *(const float4*)(nx_ + 12); } while (0)

    #define CONVERT(RA, RB, RC, RD, BUF) do {                                \
        uint4 o0_, o1_;                                                      \
        o0_.x = pk2(RA.x, RA.y); o0_.y = pk2(RA.z, RA.w);                    \
        o0_.z = pk2(RB.x, RB.y); o0_.w = pk2(RB.z, RB.w);                    \
        o1_.x = pk2(RC.x, RC.y); o1_.y = pk2(RC.z, RC.w);                    \
        o1_.z = pk2(RD.x, RD.y); o1_.w = pk2(RD.z, RD.w);                    \
        *(uint4*)((char*)As[BUF] + sb0) = o0_;                               \
        *(uint4*)((char*)As[BUF] + sb1) = o1_; } while (0)

    #define LOADB(SET, KG) do {                                              \
        const int kg_ = (KG) < 31 ? (KG) : 31;                               \
        _Pragma("unroll")                                                    \
        for (int cf = 0; cf < 8; ++cf)                                       \
            SET[cf] = *(const short8*)(Wt                                    \
                + ((size_t)((etb + cf) * 32 + kg_)) * 512 + lane * 8);       \
    } while (0)

    // one kk-step: prefetch B(kg+1) into LD, MFMA with USE (A from LDS)
    #define KK(Q, K, CUR, LD, USE) do {                                      \
        LOADB(LD, (Q) * 4 + (K) + 1);                                        \
        short8 af[2];                                                        \
        _Pragma("unroll")                                                    \
        for (int rf = 0; rf < 2; ++rf) {                                     \
            int r_ = wr * 32 + rf * 16 + l15;                                \
            int p_ = r_ * 2 + ((K) >> 1);                                    \
            int g_ = ((K) & 1) * 4 + lhi;                                    \
            af[rf] = *(const short8*)((const char*)As[CUR]                   \
                       + p_ * 128 + ((g_ * 16) ^ ((p_ & 7) << 4)));          \
        }                                                                    \
        __builtin_amdgcn_s_setprio(1);                                       \
        _Pragma("unroll")                                                    \
        for (int rf = 0; rf < 2; ++rf)                                       \
            _Pragma("unroll")                                                \
            for (int cf = 0; cf < 8; ++cf)                                   \
                acc[rf][cf] = __builtin_amdgcn_mfma_f32_16x16x32_bf16(       \
                    af[rf], USE[cf], acc[rf][cf], 0, 0, 0);                  \
        __builtin_amdgcn_s_setprio(0);                                       \
    } while (0)

    #define COMPUTE(Q, CUR) do {                                             \
        KK(Q, 0, CUR, BB, BA);                                               \
        KK(Q, 1, CUR, BA, BB);                                               \
        KK(Q, 2, CUR, BB, BA);                                               \
        KK(Q, 3, CUR, BA, BB);  /* loads (Q+1)*4 -> BA, next phase kk0 */    \
    } while (0)

    // ---- prologue: panel0 -> buf0 now; panel1 loads in flight; B(kg0) ----
    ISSUE0(0);
    CONVERT(s0a, s0b, s0c, s0d, 0);
    ISSUE1(1);
    LOADB(BA, 0);
    __syncthreads();

    for (int q2 = 0; q2 < 4; ++q2) {
        // even phase q = 2*q2: compute buf0; issue S0 <- panel q+2;
        // convert S1 (panel q+1) -> buf1
        {
            const int q = 2 * q2;
            if (q + 2 < NPH) ISSUE0(q + 2);
            COMPUTE(q, 0);
            CONVERT(s1a, s1b, s1c, s1d, 1);
            __syncthreads();
        }
        // odd phase q = 2*q2+1: compute buf1; issue S1 <- panel q+2;
        // convert S0 (panel q+1) -> buf0
        {
            const int q = 2 * q2 + 1;
            if (q + 2 < NPH) ISSUE1(q + 2);
            COMPUTE(q, 1);
            if (q + 1 < NPH) CONVERT(s0a, s0b, s0c, s0d, 0);
            __syncthreads();
        }
    }

    // ---- epilogue: tanh + Va-weighted reduction over this wave's 128 cols --
    // C/D layout (m89-verified): col = lane&15, row = (lane>>4)*4 + reg
    float sp[2][4];
    #pragma unroll
    for (int rf = 0; rf < 2; ++rf)
        #pragma unroll
        for (int j = 0; j < 4; ++j) sp[rf][j] = 0.f;

    #pragma unroll
    for (int cf = 0; cf < 8; ++cf) {
        int e = e0 + cf * 16 + l15;
        float offv = off[b * D_DIM + e];
        float vav  = Va[e];
        #pragma unroll
        for (int rf = 0; rf < 2; ++rf)
            #pragma unroll
            for (int j = 0; j < 4; ++j) {
                float x = acc[rf][cf][j] + offv;
                sp[rf][j] += fast_tanh(x) * vav;
            }
    }

    #pragma unroll
    for (int rf = 0; rf < 2; ++rf)
        #pragma unroll
        for (int j = 0; j < 4; ++j) {
            float v = sp[rf][j];
            v += __shfl_xor(v, 1, 64);
            v += __shfl_xor(v, 2, 64);
            v += __shfl_xor(v, 4, 64);
            v += __shfl_xor(v, 8, 64);
            if (l15 == 0)
                atomicAdd(&score_lds[wr * 32 + rf * 16 + lhi * 4 + j], v);
        }
    __syncthreads();

    if (t < 64) scores[(size_t)hh * M_TOTAL + row0 + t] = score_lds[t];
}

// ---------------------------------------------------------------------------
// Masked softmax over S=4096 per batch row; sums the two column-half partials.
__global__ __launch_bounds__(256) void softmax_kernel(
        const float* __restrict__ scores, const void* __restrict__ mask,
        const int* __restrict__ flag, float* __restrict__ out) {
    __shared__ float red[4];
    const int b = blockIdx.x, t = threadIdx.x;
    const float* s0 = scores + (size_t)b * S_DIM;
    const float* s1 = scores + (size_t)M_TOTAL + (size_t)b * S_DIM;
    const int mode8 = flag[0];

    float v[16];
    float mx = -INFINITY;
    if (mode8) {
        const unsigned char* m = (const unsigned char*)mask + (size_t)b * S_DIM;
        #pragma unroll
        for (int i = 0; i < 16; ++i) {
            int idx = i * 256 + t;
            v[i] = m[idx] ? (s0[idx] + s1[idx]) : -INFINITY;
            mx = fmaxf(mx, v[i]);
        }
    } else {
        const int* m = (const int*)mask + (size_t)b * S_DIM;
        #pragma unroll
        for (int i = 0; i < 16; ++i) {
            int idx = i * 256 + t;
            v[i] = m[idx] ? (s0[idx] + s1[idx]) : -INFINITY;
            mx = fmaxf(mx, v[i]);
        }
    }
    #pragma unroll
    for (int k = 1; k <= 32; k <<= 1) mx = fmaxf(mx, __shfl_xor(mx, k, 64));
    if ((t & 63) == 0) red[t >> 6] = mx;
    __syncthreads();
    mx = fmaxf(fmaxf(red[0], red[1]), fmaxf(red[2], red[3]));
    __syncthreads();

    float sum = 0.f;
    #pragma unroll
    for (int i = 0; i < 16; ++i) {
        v[i] = __expf(v[i] - mx);     // exp(-inf)=0 for masked slots
        sum += v[i];
    }
    #pragma unroll
    for (int k = 1; k <= 32; k <<= 1) sum += __shfl_xor(sum, k, 64);
    if ((t & 63) == 0) red[t >> 6] = sum;
    __syncthreads();
    sum = red[0] + red[1] + red[2] + red[3];
    float inv = 1.f / sum;
    #pragma unroll
    for (int i = 0; i < 16; ++i) out[(size_t)b * S_DIM + i * 256 + t] = v[i] * inv;
}

// ---------------------------------------------------------------------------
extern "C" void kernel_launch(void* const* d_in, const int* in_sizes, int n_in,
                              void* d_out, int out_size, void* d_ws, size_t ws_size,
                              hipStream_t stream) {
    const float* enc  = (const float*)d_in[0];   // [32][4096][1024]
    const float* dech = (const float*)d_in[1];   // [1][32][1024]
    const void*  mask = d_in[2];                 // [32][4096] bool-or-int32
    const float* Wa_w = (const float*)d_in[3];   // [1024][1024]
    const float* Wa_b = (const float*)d_in[4];   // [1024]
    const float* Ua_w = (const float*)d_in[5];   // [1024][1024]
    const float* Ua_b = (const float*)d_in[6];   // [1024]
    const float* Va_w = (const float*)d_in[7];   // [1][1024]
    // d_in[8] = Va_b: constant shift -> cancels in softmax.
    float* out = (float*)d_out;

    char* ws = (char*)d_ws;
    unsigned short* Wt = (unsigned short*)ws;                       // 2 MiB tiled
    float* off    = (float*)(ws + (1u << 21));                      // 128 KiB
    float* scores = (float*)(ws + (1u << 21) + (1u << 17));         // 2 x 512 KiB
    int*   flag   = (int*)(ws + (1u << 21) + (1u << 17) + (1u << 20));

    hipLaunchKernelGGL(mask_detect_kernel, dim3(1), dim3(256), 0, stream,
                       (const unsigned int*)mask, flag);
    hipLaunchKernelGGL(wconv_kernel, dim3(512), dim3(256), 0, stream, Wa_w, Wt);
    hipLaunchKernelGGL(off_kernel, dim3(1024), dim3(256), 0, stream,
                       dech, Ua_w, Ua_b, Wa_b, off);
    hipLaunchKernelGGL(score_kernel, dim3(4096), dim3(512), 0, stream,
                       enc, Wt, off, Va_w, scores);
    hipLaunchKernelGGL(softmax_kernel, dim3(B_DIM), dim3(256), 0, stream,
                       scores, mask, flag, out);
}